// Round 11
// baseline (265.659 us; speedup 1.0000x reference)
//
#include <hip/hip_runtime.h>
#include <hip/hip_bf16.h>

#define EPSV 1e-5f

// workspace layout: [wB2][xTp][stats]
#define WB2_ELEMS (2*8*36*128*32)          // [p][nt(8)][kt(36)][nl(128)][kk(32)] bf16
#define WB2_BYTES ((size_t)WB2_ELEMS*2)    // 4,718,592
#define XTP_ELEMS (8*68*68*128)            // padded channels-last x, bf16
#define XTP_BYTES ((size_t)XTP_ELEMS*2)    // 9,469,952
#define STATS_OFF (WB2_BYTES + XTP_BYTES)  // 1024 float2 partials

// k_conv dynamic LDS: A halo 400px*256B + 3 B-buffers of 8 KB
#define ATILE_ELEMS (400*128)              // 102,400 B
#define CONV_LDS_BYTES (ATILE_ELEMS*2 + 3*8192)   // 126,976 B

typedef __attribute__((ext_vector_type(8))) short short8;
typedef __attribute__((ext_vector_type(4))) float f32x4;

__device__ __forceinline__ void gload_lds16(const void* g, void* l) {
    __builtin_amdgcn_global_load_lds(
        (const __attribute__((address_space(1))) void*)g,
        (__attribute__((address_space(3))) void*)l, 16, 0, 0);
}

// ---------------------------------------------------------------------------
// x [8][128][64][64] f32  ->  xTp [8][68][68][128] bf16 (2-px zero halo)
__global__ __launch_bounds__(256) void k_xpad(const float* __restrict__ x,
                                              __hip_bfloat16* __restrict__ xTp) {
    int bh = blockIdx.x; int b = bh >> 6, h = bh & 63;
    __shared__ __hip_bfloat16 tile[64][130];
    int t = threadIdx.x;
#pragma unroll
    for (int i = 0; i < 32; ++i) {
        int e = (i << 8) + t; int w = e & 63; int ci = e >> 6;
        tile[w][ci] = __float2bfloat16(x[(((size_t)(b*128 + ci))*64 + h)*64 + w]);
    }
    __syncthreads();
    __hip_bfloat16* dst = xTp + ((size_t)((b*68 + h + 2)*68 + 2))*128;
#pragma unroll
    for (int i = 0; i < 32; ++i) {
        int e = (i << 8) + t; int ci = e & 127; int w = e >> 7;
        dst[w*128 + ci] = tile[w][ci];
    }
}

// ---------------------------------------------------------------------------
// w_mid [128][16][128][3][3] f32 -> wB2 [p][nt(8)][kt(36)][nl(128)][kk(32)]
__global__ void k_wrepack(const float* __restrict__ w_mid,
                          __hip_bfloat16* __restrict__ wB2) {
    int idx = blockIdx.x * 256 + threadIdx.x;
    if (idx >= WB2_ELEMS) return;
    int kk  = idx & 31;
    int nl  = (idx >> 5) & 127;
    int q   = idx >> 12;             // (p*8+nt)*36 + kt
    int kt  = q % 36;
    int pnt = q / 36;
    int nt  = pnt & 7, p = pnt >> 3;
    int c = ((nt*8 + (nl >> 4)) << 1) + p;
    int m = nl & 15;
    int k = kt*32 + kk;
    int tap = k >> 7, ci = k & 127;
    wB2[idx] = __float2bfloat16(w_mid[((size_t)((c*16 + m)*128 + ci))*9 + tap]);
}

// ---------------------------------------------------------------------------
// Persistent-A implicit-GEMM conv, 512 threads (8 waves: 4M x 2N).
// Block = one (p, nt) x one 16x16 output tile (M=256). A halo 20x20x128
// staged ONCE (R8-proven reg+ds_write, swizzle phys16Bslot = log ^ (pix&7)).
// B: 36 steps x 8 KB via global_load_lds into 3 rotating buffers,
// counted vmcnt(1) (R10-proven scheme), one s_barrier per step.
__global__ __launch_bounds__(512) void k_conv(
    const __hip_bfloat16* __restrict__ xTp,
    const __hip_bfloat16* __restrict__ wB2,
    const float* __restrict__ w_pt,
    const float* __restrict__ b_pt,
    float* __restrict__ y) {
    extern __shared__ __hip_bfloat16 smem[];
    __hip_bfloat16* Atile = smem;                  // 400*128 elems
    __hip_bfloat16* Blds  = smem + ATILE_ELEMS;    // 3 * 4096 elems

    // XCD x owns pnt range (x&1)*8..+8 and mt range (x>>1)*32..+32:
    // per-XCD working set = B 2.3 MB + A 2.4 MB.
    const int x_  = blockIdx.x & 7;        // XCD (round-robin)
    const int i_  = blockIdx.x >> 3;       // 0..255
    const int pnt = (x_ & 1)*8 + (i_ >> 5);
    const int mt  = (x_ >> 1)*32 + (i_ & 31);
    const int p   = pnt & 1;
    const int nt  = pnt >> 1;
    const int dil = 1 + p;
    const int b   = mt >> 4;               // image
    const int hb  = (mt >> 2) & 3;         // row-block
    const int wb  = mt & 3;                // col-block
    const int H0  = hb*16, W0 = wb*16;     // halo rows/cols H0..H0+19 (padded)

    const int t = threadIdx.x, lane = t & 63, wave = t >> 6;
    const int wm = wave >> 1, wn = wave & 1;   // 4 M-waves x 2 N-waves
    const int lm = lane & 15, lg = lane >> 4;

    // ---- stage A halo once: 400 px x 16 slots = 6400, 512 thr, 13 passes ----
    {
        const size_t gbase = ((size_t)(b*68 + H0))*68 + W0;
#pragma unroll
        for (int pass = 0; pass < 13; ++pass) {
            int si = pass*512 + t;
            if (si < 6400) {
                int pix = si >> 4;
                int ls  = si & 15;
                int prow = pix / 20, pcol = pix - prow*20;
                short8 v = *(const short8*)(xTp + (gbase + prow*68 + pcol)*128 + ls*8);
                *(short8*)(Atile + pix*128 + ((ls ^ (pix & 7)) << 3)) = v;
            }
        }
    }

    // ---- B staging setup (R10 formulas; 512 thr = 1 slot/thread/step) ----
    const int rsub = t >> 2;                              // row 0..127
    const int ksub = (((t & 3) ^ ((t >> 3) & 3)) << 3);   // src-side swizzled slot
    const __hip_bfloat16* bsrc = wB2 + (size_t)p*(8*36*4096) + (size_t)nt*(36*4096)
                               + rsub*32 + ksub;
#define ISSUE_B(u, bufi) \
    gload_lds16(bsrc + (size_t)(u)*4096, (char*)Blds + (bufi)*8192 + t*16)

    f32x4 acc[4][4];
#pragma unroll
    for (int i = 0; i < 4; ++i)
#pragma unroll
        for (int j = 0; j < 4; ++j) acc[i][j] = (f32x4){0.f, 0.f, 0.f, 0.f};

    // B fragment read offsets (R10 read-side swizzle)
    const int sslot = (lg ^ ((lm >> 1) & 3)) << 3;
    int boff[4];
#pragma unroll
    for (int j = 0; j < 4; ++j)
        boff[j] = (wn*64 + j*16 + lm)*32 + sslot;

    // prologue: issue B steps 0,1 (drained by the syncthreads — one-time cost)
    ISSUE_B(0, 0);
    ISSUE_B(1, 1);
    __syncthreads();    // A halo + B0/B1 visible

    // A fragment read (R8-proven LOADA): frag i = output row wm*4+i, col lm
#define LOADA(af, khc, kwc, kcc) do {                                         \
    int pc_ = 2 + dil*(kwc) + lm;                                             \
    int pr_ = (wm*4 + 2 + dil*(khc))*20 + pc_;                                \
    int px0 = pr_;      af[0] = *(const short8*)(Atile + px0*128 + ((((kcc)*4 + lg) ^ (px0 & 7)) << 3)); \
    int px1 = pr_ + 20; af[1] = *(const short8*)(Atile + px1*128 + ((((kcc)*4 + lg) ^ (px1 & 7)) << 3)); \
    int px2 = pr_ + 40; af[2] = *(const short8*)(Atile + px2*128 + ((((kcc)*4 + lg) ^ (px2 & 7)) << 3)); \
    int px3 = pr_ + 60; af[3] = *(const short8*)(Atile + px3*128 + ((((kcc)*4 + lg) ^ (px3 & 7)) << 3)); \
  } while (0)

#pragma unroll
    for (int u = 0; u < 36; ++u) {
        const int bi  = u % 3;
        const int bi2 = (u + 2) % 3;
        // wait for step u's B load (leave u+1's in flight); tail: drain
        if (u < 35) asm volatile("s_waitcnt vmcnt(1)" ::: "memory");
        else        asm volatile("s_waitcnt vmcnt(0)" ::: "memory");
        __builtin_amdgcn_s_barrier();
        __builtin_amdgcn_sched_barrier(0);
        if (u + 2 < 36) ISSUE_B(u + 2, bi2);

        const int tap = u >> 2, kc = u & 3;
        const int kh = tap/3 - 1, kw = tap%3 - 1;    // compile-time
        short8 af[4], bf[4];
        LOADA(af, kh, kw, kc);
#pragma unroll
        for (int j = 0; j < 4; ++j)
            bf[j] = *(const short8*)(Blds + bi*4096 + boff[j]);
        __builtin_amdgcn_s_setprio(1);
#pragma unroll
        for (int i = 0; i < 4; ++i)
#pragma unroll
            for (int j = 0; j < 4; ++j)
                acc[i][j] = __builtin_amdgcn_mfma_f32_16x16x32_bf16(
                    af[i], bf[j], acc[i][j], 0, 0, 0);
        __builtin_amdgcn_s_setprio(0);
    }
#undef ISSUE_B
#undef LOADA

    // epilogue: leaky -> *w_pt -> 16-lane reduce -> +b_pt -> y (plain stores)
#pragma unroll
    for (int j = 0; j < 4; ++j) {
        int n_g = nt*128 + wn*64 + j*16 + lm;
        int c = ((n_g >> 4) << 1) + p;     // uniform across the 16-lane group
        float wp = w_pt[c*16 + lm];        // m == lm
        float bp = b_pt[c];
#pragma unroll
        for (int i = 0; i < 4; ++i) {
            int h = H0 + wm*4 + i;
#pragma unroll
            for (int r = 0; r < 4; ++r) {
                float v = acc[i][j][r];
                v = v >= 0.f ? v : 0.1f*v;
                v *= wp;
                v += __shfl_xor(v, 1);
                v += __shfl_xor(v, 2);
                v += __shfl_xor(v, 4);
                v += __shfl_xor(v, 8);
                if (lm == 0) {
                    int w = W0 + lg*4 + r;
                    y[(size_t)(b*128 + c)*4096 + h*64 + w] = v + bp;
                }
            }
        }
    }
}

// ---------------------------------------------------------------------------
// per-(b,c)-plane partial sums (float4 loads, no atomics, deterministic)
__global__ __launch_bounds__(256) void k_ystat(const float* __restrict__ y,
                                               float2* __restrict__ partials) {
    int P = blockIdx.x;                 // plane = b*128 + c
    const float4* base = (const float4*)(y + (size_t)P*4096);
    int t = threadIdx.x;
    float s = 0.f, s2 = 0.f;
#pragma unroll
    for (int i = 0; i < 4; ++i) {
        float4 v = base[t + i*256];
        s  += v.x + v.y + v.z + v.w;
        s2 += v.x*v.x + v.y*v.y + v.z*v.z + v.w*v.w;
    }
#pragma unroll
    for (int o = 32; o; o >>= 1) { s += __shfl_down(s, o); s2 += __shfl_down(s2, o); }
    __shared__ float ss[4], ss2[4];
    if ((t & 63) == 0) { ss[t >> 6] = s; ss2[t >> 6] = s2; }
    __syncthreads();
    if (t == 0)
        partials[P] = make_float2(ss[0]+ss[1]+ss[2]+ss[3], ss2[0]+ss2[1]+ss2[2]+ss2[3]);
}

// BN finalize + apply + ReLU. Block covers 256 float4 = quarter of one plane.
__global__ __launch_bounds__(256) void k_bn_apply(float* __restrict__ y,
                                                  const float2* __restrict__ partials,
                                                  const float* __restrict__ gamma,
                                                  const float* __restrict__ beta) {
    int bid = blockIdx.x;
    int c = (bid >> 2) & 127;
    float s = 0.f, s2 = 0.f;
#pragma unroll
    for (int b = 0; b < 8; ++b) {
        float2 pr = partials[b*128 + c];
        s += pr.x; s2 += pr.y;
    }
    float mean = s * (1.f/32768.f);
    float var  = s2 * (1.f/32768.f) - mean*mean;
    float scale = gamma[c] * rsqrtf(var + EPSV);
    float shift = beta[c] - mean*scale;
    float4* y4 = (float4*)y;
    int idx = bid*256 + threadIdx.x;
    float4 v = y4[idx];
    v.x = fmaxf(v.x*scale + shift, 0.f);
    v.y = fmaxf(v.y*scale + shift, 0.f);
    v.z = fmaxf(v.z*scale + shift, 0.f);
    v.w = fmaxf(v.w*scale + shift, 0.f);
    y4[idx] = v;
}

// ---------------------------------------------------------------------------
extern "C" void kernel_launch(void* const* d_in, const int* in_sizes, int n_in,
                              void* d_out, int out_size, void* d_ws, size_t ws_size,
                              hipStream_t stream) {
    const float* x     = (const float*)d_in[0];
    const float* w_mid = (const float*)d_in[1];
    const float* w_pt  = (const float*)d_in[2];
    const float* b_pt  = (const float*)d_in[3];
    const float* gamma = (const float*)d_in[4];
    const float* beta  = (const float*)d_in[5];
    float* y = (float*)d_out;

    __hip_bfloat16* wB2 = (__hip_bfloat16*)d_ws;
    __hip_bfloat16* xTp = (__hip_bfloat16*)((char*)d_ws + WB2_BYTES);
    float2* partials    = (float2*)((char*)d_ws + STATS_OFF);

    // opt in to >64 KB dynamic LDS for k_conv (host-side, idempotent)
    (void)hipFuncSetAttribute((const void*)k_conv,
                              hipFuncAttributeMaxDynamicSharedMemorySize,
                              CONV_LDS_BYTES);

    hipMemsetAsync(xTp, 0, XTP_BYTES, stream);                  // zero halo
    k_xpad<<<512, 256, 0, stream>>>(x, xTp);
    k_wrepack<<<(WB2_ELEMS + 255) / 256, 256, 0, stream>>>(w_mid, wB2);
    k_conv<<<2048, 512, CONV_LDS_BYTES, stream>>>(xTp, wB2, w_pt, b_pt, y);
    k_ystat<<<1024, 256, 0, stream>>>(y, partials);
    k_bn_apply<<<4096, 256, 0, stream>>>(y, partials, gamma, beta);
}